// Round 7
// baseline (540.721 us; speedup 1.0000x reference)
//
#include <hip/hip_runtime.h>
#include <hip/hip_bf16.h>

// BinaryLinear: out = x @ sign(W)^T
// x: [32,4096,1024] f32 -> A [M=131072][K=1024]
// W: [1024,1024] f32    -> B^T = sign(W) [N=1024][K=1024] bf16 in d_ws (once)
// out: [M][N] f32
//
// R7: R6 (453us) is latency-bound: single-buffer serializes stage->drain->
// barrier->compute (BW floor is 164us). Restore double-buffer as T3's minimum
// 2-phase, WITH the explicit vmcnt(0) drain R6 proved necessary (R5's replay
// race = compiler __syncthreads not draining gll vmcnt):
//   prologue: STAGE(buf0,0); vmcnt(0); barrier
//   step kk : STAGE(buf^1, kk+1); compute(buf); asm vmcnt(0); barrier
// Reads of a buffer complete before the end-of-step barrier that precedes its
// re-staging -> race-free with ONE barrier per step. BK=32 so dbuf = 48KB ->
// 3 blocks/CU. Addressing/swizzles = R5/R6 family (0 bank conflicts measured).

typedef __attribute__((ext_vector_type(8))) short bf16x8;
typedef __attribute__((ext_vector_type(4))) float f32x4;

#define BM 128
#define BN 128
#define BK 32
#define KDIM 1024
#define NDIM 1024
#define NKSTEP (KDIM / BK)

__device__ __forceinline__ unsigned cvt2(float a, float b) {
  unsigned r;
  asm("v_cvt_pk_bf16_f32 %0, %1, %2" : "=v"(r) : "v"(a), "v"(b));
  return r;
}

// ---- pre-kernel: Bs[n][k] = sign(W[n][k]) as bf16 (+1, -1, or 0) ----
__global__ void sign_kernel(const float4* __restrict__ W, ushort4* __restrict__ Bs, int n4) {
  int i = blockIdx.x * blockDim.x + threadIdx.x;
  if (i >= n4) return;
  float4 v = W[i];
  const float* pv = (const float*)&v;
  ushort4 r;
  unsigned short* pr = (unsigned short*)&r;
#pragma unroll
  for (int j = 0; j < 4; ++j) {
    union { float f; unsigned int u; } c; c.f = pv[j];
    pr[j] = ((c.u & 0x7fffffffu) == 0u)
                ? (unsigned short)0
                : (unsigned short)(0x3f80u | ((c.u >> 16) & 0x8000u));
  }
  Bs[i] = r;
}

// ---- main GEMM ----
__global__ __launch_bounds__(256, 3) void bgemm_kernel(
    const float* __restrict__ X,
    const unsigned short* __restrict__ Bs,
    float* __restrict__ O) {
  // per buffer: A 128x8 f32x4 chunks (16KB) + B 128x32 bf16 (8KB) = 24KB; x2 = 48KB
  __shared__ f32x4 sA[2][BM * 8];
  __shared__ unsigned short sB[2][BN * BK];

  const int t = threadIdx.x;
  const int l = t & 63;
  const int w = t >> 6;
  const int wr = w >> 1;  // 2x2 wave grid, wave tile 64x64
  const int wc = w & 1;

  // XCD-bijective swizzle; bn fastest => 8 N-sharers of an M-tile on one XCD.
  const unsigned nwg = gridDim.x;
  unsigned swz = blockIdx.x;
  if ((nwg & 7u) == 0u) swz = (blockIdx.x & 7u) * (nwg >> 3) + (blockIdx.x >> 3);
  const int bm = (int)(swz >> 3);
  const int bn = (int)(swz & 7u);
  const size_t m0 = (size_t)bm * BM;
  const int N0 = bn * BN;

  // A staging: 128x32 f32 = 1024 16B-chunks, 4 gll/thread.
  // LDS chunk c = r*8 + s holds global k-chunk q = s ^ (r&7)  (both-sides XOR).
  const float* agp[4];
#pragma unroll
  for (int i = 0; i < 4; ++i) {
    int c = i * 256 + t;
    int r = c >> 3;
    int q = (c & 7) ^ (r & 7);
    agp[i] = X + (m0 + (size_t)r) * KDIM + q * 4;
  }

  // B staging: 128x32 bf16 = 512 16B-chunks, 2 gll/thread.
  // LDS chunk c = n*4 + s holds global k-octet q = s ^ ((n>>1)&3).
  const unsigned short* bgp[2];
#pragma unroll
  for (int i = 0; i < 2; ++i) {
    int c = i * 256 + t;
    int n = c >> 2;
    int q = (c & 3) ^ ((n >> 1) & 3);
    bgp[i] = Bs + (size_t)(N0 + n) * KDIM + q * 8;
  }

  // fragment read offsets
  const int ll = l & 15;
  const int kb = l >> 4;
  int idxA[4];  // f32x4-chunk index of low half of k-octet; high = ^1
#pragma unroll
  for (int i = 0; i < 4; ++i) {
    int row = wr * 64 + i * 16 + ll;
    idxA[i] = row * 8 + ((kb * 2) ^ (row & 7));
  }
  int offB[4];
#pragma unroll
  for (int j = 0; j < 4; ++j) {
    int n = wc * 64 + j * 16 + ll;
    int q = kb ^ ((n >> 1) & 3);
    offB[j] = n * BK + q * 8;
  }

  f32x4 acc[4][4];
#pragma unroll
  for (int i = 0; i < 4; ++i)
#pragma unroll
    for (int j = 0; j < 4; ++j) acc[i][j] = (f32x4)0.0f;

#define STAGE(buf, k0)                                                         \
  do {                                                                         \
    _Pragma("unroll") for (int i = 0; i < 4; ++i)                              \
        __builtin_amdgcn_global_load_lds(                                      \
            (const __attribute__((address_space(1))) void*)(agp[i] + (k0)),    \
            (__attribute__((address_space(3))) void*)(&sA[buf][i * 256 + t]),  \
            16, 0, 0);                                                         \
    _Pragma("unroll") for (int i = 0; i < 2; ++i)                              \
        __builtin_amdgcn_global_load_lds(                                      \
            (const __attribute__((address_space(1))) void*)(bgp[i] + (k0)),    \
            (__attribute__((address_space(3))) void*)(&sB[buf][(i * 256 + t) * 8]), \
            16, 0, 0);                                                         \
  } while (0)

  // prologue
  STAGE(0, 0);
  asm volatile("s_waitcnt vmcnt(0) lgkmcnt(0)" ::: "memory");
  __syncthreads();

#define STEP(CUR)                                                              \
  {                                                                            \
    if (kk + 1 < NKSTEP) STAGE((CUR) ^ 1, (kk + 1) * BK);                      \
    const unsigned short* sb = sB[CUR];                                        \
    bf16x8 bv[4];                                                              \
    _Pragma("unroll") for (int j = 0; j < 4; ++j)                              \
        bv[j] = *reinterpret_cast<const bf16x8*>(sb + offB[j]);                \
    bf16x8 av[4];                                                              \
    _Pragma("unroll") for (int i = 0; i < 4; ++i) {                            \
      f32x4 c0 = sA[CUR][idxA[i]];                                             \
      f32x4 c1 = sA[CUR][idxA[i] ^ 1];                                         \
      union { uint4 u; bf16x8 v; } cv;                                         \
      cv.u.x = cvt2(c0.x, c0.y); cv.u.y = cvt2(c0.z, c0.w);                    \
      cv.u.z = cvt2(c1.x, c1.y); cv.u.w = cvt2(c1.z, c1.w);                    \
      av[i] = cv.v;                                                            \
    }                                                                          \
    _Pragma("unroll") for (int i = 0; i < 4; ++i)                              \
        _Pragma("unroll") for (int j = 0; j < 4; ++j)                          \
            acc[i][j] = __builtin_amdgcn_mfma_f32_16x16x32_bf16(               \
                av[i], bv[j], acc[i][j], 0, 0, 0);                             \
    asm volatile("s_waitcnt vmcnt(0)" ::: "memory");                           \
    __syncthreads();                                                           \
    ++kk;                                                                      \
  }

  int kk = 0;
  while (kk < NKSTEP) {
    STEP(0)
    STEP(1)
  }
#undef STEP
#undef STAGE

  // epilogue: C/D layout col = lane&15, row = (lane>>4)*4 + reg
  const int crow = kb * 4;
#pragma unroll
  for (int i = 0; i < 4; ++i) {
    const size_t r0 = m0 + wr * 64 + i * 16 + crow;
#pragma unroll
    for (int j = 0; j < 4; ++j) {
      const int col = N0 + wc * 64 + j * 16 + ll;
      float* op = O + r0 * NDIM + col;
#pragma unroll
      for (int e = 0; e < 4; ++e) op[(size_t)e * NDIM] = acc[i][j][e];
    }
  }
}

// ---- fallback (only if ws too small for the 2 MiB sign buffer) ----
__global__ void naive_kernel(const float* __restrict__ X, const float* __restrict__ W,
                             float* __restrict__ O, long long total) {
  long long idx = (long long)blockIdx.x * blockDim.x + threadIdx.x;
  if (idx >= total) return;
  int n = (int)(idx & (NDIM - 1));
  long long m = idx >> 10;
  const float* xr = X + m * KDIM;
  const float* wr = W + (long long)n * KDIM;
  float s = 0.f;
  for (int k = 0; k < KDIM; ++k) {
    float wv = wr[k];
    float sg = (wv > 0.f) ? 1.f : ((wv < 0.f) ? -1.f : 0.f);
    s += xr[k] * sg;
  }
  O[idx] = s;
}

extern "C" void kernel_launch(void* const* d_in, const int* in_sizes, int n_in,
                              void* d_out, int out_size, void* d_ws, size_t ws_size,
                              hipStream_t stream) {
  const float* X = (const float*)d_in[0];
  const float* W = (const float*)d_in[1];
  float* O = (float*)d_out;
  const long long M = (long long)in_sizes[0] / KDIM;  // 131072

  const size_t need_ws = (size_t)NDIM * KDIM * sizeof(unsigned short);  // 2 MiB
  if (ws_size >= need_ws && (M % BM) == 0) {
    unsigned short* Bs = (unsigned short*)d_ws;
    int n4 = (NDIM * KDIM) / 4;
    sign_kernel<<<dim3(n4 / 256), dim3(256), 0, stream>>>(
        (const float4*)W, (ushort4*)Bs, n4);
    dim3 grid((unsigned)((M / BM) * (NDIM / BN)));  // 8192
    bgemm_kernel<<<grid, dim3(256), 0, stream>>>(X, Bs, O);
  } else {
    long long total = M * NDIM;
    long long blocks = (total + 255) / 256;
    naive_kernel<<<dim3((unsigned)blocks), dim3(256), 0, stream>>>(X, W, O, total);
  }
}